// Round 8
// baseline (255.390 us; speedup 1.0000x reference)
//
#include <hip/hip_runtime.h>

#define N_NODES 10000
#define E_EDGES 640000
#define IN_CH   512
#define OUT_CH  256
#define HALF_CH 128
#define CSR_CAP (E_EDGES + 16 * N_NODES + 128)  // pad-16 capacity + prefetch slack (u16 entries)
#define G_GEMM_X 157                            // ceil(10000/64)
#define G_GEMM  (G_GEMM_X * 2)                  // x2 planes
#define HBLK    125                             // histogram/scatter chunks
#define EPB     5120                            // edges per chunk: 125*5120 = 640000
#define G_SCALE 2500                            // scale blocks: 4 nodes each

typedef short bf16x8 __attribute__((ext_vector_type(8)));
typedef float f32x4  __attribute__((ext_vector_type(4)));

__device__ __forceinline__ unsigned short f2b(float f) {
    unsigned int u = __float_as_uint(f);
    return (unsigned short)((u + 0x7FFFu + ((u >> 16) & 1u)) >> 16);
}
__device__ __forceinline__ float lo16(unsigned int u) { return __uint_as_float(u << 16); }
__device__ __forceinline__ float hi16(unsigned int u) { return __uint_as_float(u & 0xFFFF0000u); }
__device__ __forceinline__ float b2f(unsigned short u) { return __uint_as_float(((unsigned int)u) << 16); }

// ---------------- fused GEMM (raw f32 out) || LDS-histogram rank (R7-verified) ----------
__global__ __launch_bounds__(256) void gemm_hist(const float* __restrict__ x,
                                                 const float* __restrict__ w,
                                                 const float* __restrict__ bias,
                                                 float* __restrict__ h0f,       // [2][N][128] f32
                                                 const int* __restrict__ row,
                                                 int* __restrict__ cnt,          // [HBLK][N]
                                                 unsigned short* __restrict__ rank) {
    __shared__ __align__(16) char smem[40960];   // union: gemm tiles 27.6KB | hist 40KB
    int bid = blockIdx.x;
    int tid = threadIdx.x;
    if (bid >= G_GEMM) {
        // ---- hist path ----
        int* hist = (int*)smem;
        int b = bid - G_GEMM;
        for (int i = tid; i < N_NODES; i += 256) hist[i] = 0;
        __syncthreads();
        int ebase = b * EPB;
        for (int i = tid; i < EPB; i += 256) {
            int r = row[ebase + i];
            rank[ebase + i] = (unsigned short)atomicAdd(&hist[r], 1);
        }
        __syncthreads();
        int* cb = cnt + (size_t)b * N_NODES;
        for (int i = tid; i < N_NODES; i += 256) cb[i] = hist[i];
        return;
    }
    // ---- gemm path (verified core; raw f32 epilogue) ----
    typedef unsigned short us72[72];
    us72* As = (us72*)smem;                     // [64][72]
    us72* Bs = (us72*)(smem + 64 * 72 * 2);     // [128][72]
    int bx = bid % G_GEMM_X;
    int plane = bid / G_GEMM_X;
    int wave = tid >> 6, lane = tid & 63, quad = lane >> 4, l16 = lane & 15;
    int row0 = bx * 64;
    int n0 = plane * 128;
    float* h0f_p = h0f + (size_t)plane * N_NODES * HALF_CH;

    int ar = tid >> 2;
    int aseg = (tid & 3) * 16;
    int br = tid >> 1;
    int bseg = (tid & 1) * 32;

    f32x4 acc[8] = {};
    for (int k0 = 0; k0 < IN_CH; k0 += 64) {
        {
            int gr = row0 + ar;
            if (gr < N_NODES) {
                const float4* src = (const float4*)(x + (size_t)gr * IN_CH + k0 + aseg);
                #pragma unroll
                for (int i = 0; i < 4; i++) {
                    float4 v = src[i];
                    ushort4 o;
                    o.x = f2b(v.x); o.y = f2b(v.y); o.z = f2b(v.z); o.w = f2b(v.w);
                    *(ushort4*)&As[ar][aseg + i * 4] = o;
                }
            } else {
                ushort4 z = {0, 0, 0, 0};
                #pragma unroll
                for (int i = 0; i < 4; i++) *(ushort4*)&As[ar][aseg + i * 4] = z;
            }
        }
        {
            const float4* src = (const float4*)(w + (size_t)(n0 + br) * IN_CH + k0 + bseg);
            #pragma unroll
            for (int i = 0; i < 8; i++) {
                float4 v = src[i];
                ushort4 o;
                o.x = f2b(v.x); o.y = f2b(v.y); o.z = f2b(v.z); o.w = f2b(v.w);
                *(ushort4*)&Bs[br][bseg + i * 4] = o;
            }
        }
        __syncthreads();
        #pragma unroll
        for (int kk = 0; kk < 2; kk++) {
            bf16x8 a = *(const bf16x8*)&As[wave * 16 + l16][kk * 32 + quad * 8];
            #pragma unroll
            for (int t = 0; t < 8; t++) {
                bf16x8 b = *(const bf16x8*)&Bs[t * 16 + l16][kk * 32 + quad * 8];
                acc[t] = __builtin_amdgcn_mfma_f32_16x16x32_bf16(a, b, acc[t], 0, 0, 0);
            }
        }
        __syncthreads();
    }
    #pragma unroll
    for (int t = 0; t < 8; t++) {
        int lcol = t * 16 + l16;
        float bv = bias[n0 + lcol];
        #pragma unroll
        for (int r = 0; r < 4; r++) {
            int grow = row0 + wave * 16 + quad * 4 + r;
            if (grow < N_NODES)
                h0f_p[(size_t)grow * HALF_CH + lcol] = acc[t][r] + bv;
        }
    }
}

// ---------------- alloc_a: wave/row, NO atomics ----------------
__global__ __launch_bounds__(256) void alloc_a(int* __restrict__ cnt,   // [HBLK][N]
                                               int2* __restrict__ pd,
                                               float* __restrict__ dinv, float* __restrict__ sq,
                                               int* __restrict__ pads, int n) {
    int r = blockIdx.x * 4 + (threadIdx.x >> 6);
    int lane = threadIdx.x & 63;
    if (r >= n) return;
    int v0 = cnt[(size_t)lane * N_NODES + r];                               // b = lane
    int v1 = (lane < HBLK - 64) ? cnt[(size_t)(64 + lane) * N_NODES + r] : 0;
    int s0 = v0, s1 = v1;                                // inclusive scans over b
    #pragma unroll
    for (int off = 1; off < 64; off <<= 1) {
        int t0 = __shfl_up(s0, off, 64);
        int t1 = __shfl_up(s1, off, 64);
        if (lane >= off) { s0 += t0; s1 += t1; }
    }
    int tot0 = __shfl(s0, 63, 64);
    int d = tot0 + __shfl(s1, 63, 64);
    int pad = (d + 15) & ~15;
    cnt[(size_t)lane * N_NODES + r] = s0 - v0;           // local exclusive base, b=lane
    if (lane < HBLK - 64) cnt[(size_t)(64 + lane) * N_NODES + r] = tot0 + s1 - v1;
    if (lane == 0) {
        dinv[r] = (d > 0) ? rsqrtf((float)d) : 0.0f;
        sq[r]   = (d > 0) ? sqrtf((float)d) : 0.0f;
        pd[r] = make_int2(d, pad);
        pads[r] = pad;
    }
}

// ---------------- scan_pads: single-block exclusive scan of 10000 pads ----------------
__global__ __launch_bounds__(1024) void scan_pads(const int* __restrict__ pads,
                                                  int* __restrict__ rowstart, int n) {
    __shared__ int ls[1024];
    int t = threadIdx.x;
    int base = t * 10;                  // 1000 threads x 10 elements covers 10000
    int loc[10];
    int sum = 0;
    if (base < n) {
        #pragma unroll
        for (int i = 0; i < 10; i++) { loc[i] = pads[base + i]; sum += loc[i]; }
    }
    ls[t] = sum;
    __syncthreads();
    for (int off = 1; off < 1024; off <<= 1) {
        int v = (t >= off) ? ls[t - off] : 0;
        __syncthreads();
        ls[t] += v;
        __syncthreads();
    }
    if (base < n) {
        int run = ls[t] - sum;          // exclusive block prefix
        #pragma unroll
        for (int i = 0; i < 10; i++) { rowstart[base + i] = run; run += loc[i]; }
    }
}

// ---------------- alloc_b: wave/row — seg + sentinels (csr u16) ----------------
__global__ __launch_bounds__(256) void alloc_b(const int* __restrict__ rowstart,
                                               const int2* __restrict__ pd,
                                               int2* __restrict__ seg,
                                               unsigned short* __restrict__ csr_col, int n) {
    int r = blockIdx.x * 4 + (threadIdx.x >> 6);
    int lane = threadIdx.x & 63;
    if (r >= n) return;
    int s = rowstart[r];
    int2 pd_ = pd[r];
    if (lane == 0) seg[r] = make_int2(s, s + pd_.y);
    int j = pd_.x + lane;               // sentinels: [d, pad), <= 15 slots
    if (j < pd_.y) csr_col[s + j] = (unsigned short)N_NODES;
}

// ---------------- scatter (LDS-staged bases, u16 stores) || scale h0f -> bf16 h0b --------
__global__ __launch_bounds__(256) void scatter_scale(const int* __restrict__ row,
                                                     const int* __restrict__ col,
                                                     const int* __restrict__ base,   // [HBLK][N]
                                                     const int* __restrict__ rowstart,
                                                     const unsigned short* __restrict__ rank,
                                                     unsigned short* __restrict__ csr_col,
                                                     const float* __restrict__ h0f,  // [2][N][128]
                                                     const float* __restrict__ dinv,
                                                     unsigned short* __restrict__ h0b) {
    int bid = blockIdx.x;
    int tid = threadIdx.x;
    size_t pstride = (size_t)(N_NODES + 1) * HALF_CH;
    if (bid < HBLK) {
        // ---- scatter path: stage absolutized base row into 40KB LDS, then scatter ----
        __shared__ int bs[N_NODES];
        const int4* cb4 = (const int4*)(base + (size_t)bid * N_NODES);
        const int4* rs4 = (const int4*)rowstart;
        for (int i = tid; i < N_NODES / 4; i += 256) {   // 2500 int4, coalesced
            int4 c = cb4[i];
            int4 r = rs4[i];
            int4 o;
            o.x = c.x + r.x; o.y = c.y + r.y; o.z = c.z + r.z; o.w = c.w + r.w;
            ((int4*)bs)[i] = o;
        }
        __syncthreads();
        int ebase = bid * EPB;
        for (int i = tid; i < EPB; i += 256) {
            int e = ebase + i;
            int p = bs[row[e]] + (int)rank[e];
            csr_col[p] = (unsigned short)col[e];
        }
        return;
    }
    // ---- scale path: 4 nodes/block, both planes; single rounding f32 -> bf16 ----
    int idx = bid - HBLK;
    int node = idx * 4 + (tid >> 6);
    int lane = tid & 63;
    float di = dinv[node];
    #pragma unroll
    for (int plane = 0; plane < 2; plane++) {
        const float2* src = (const float2*)(h0f + (size_t)plane * N_NODES * HALF_CH
                                            + (size_t)node * HALF_CH);
        float2 v = src[lane];
        unsigned int o = (unsigned int)f2b(v.x * di) | ((unsigned int)f2b(v.y * di) << 16);
        ((unsigned int*)(h0b + (size_t)plane * pstride + (size_t)node * HALF_CH))[lane] = o;
    }
    // zero the pad rows (sentinel gather target) — first scale block only
    if (idx == 0 && tid < 128) {
        int plane = tid >> 6;
        ((unsigned int*)(h0b + (size_t)plane * pstride + (size_t)N_NODES * HALF_CH))[tid & 63] = 0u;
    }
}

// ---------------- SpMM: XCD-plane-partitioned, double-buffered gathers (csr u16) --------
__global__ __launch_bounds__(256) void spmm_kernel(const unsigned short* __restrict__ hb,
                                                   const int2* __restrict__ seg,
                                                   const unsigned short* __restrict__ csr_col,
                                                   const float* __restrict__ dinv,
                                                   const float* __restrict__ sq,
                                                   const unsigned short* __restrict__ prev_b,
                                                   const float* __restrict__ wts, int widx,
                                                   unsigned short* __restrict__ yb_out,
                                                   float* __restrict__ axpy_out,
                                                   unsigned short* __restrict__ axpyb_out,
                                                   int n) {
    int plane = blockIdx.x & 1;
    int node = (blockIdx.x >> 1) * 4 + (threadIdx.x >> 6);
    int lane = threadIdx.x & 63;
    if (node >= n) return;
    int sub = lane >> 4, l16 = lane & 15;
    size_t pstride = (size_t)(n + 1) * HALF_CH;
    const unsigned short* hp = hb + (size_t)plane * pstride;

    int2 se = seg[node];
    int s = se.x, e = se.y;
    float acc[8] = {0.f, 0.f, 0.f, 0.f, 0.f, 0.f, 0.f, 0.f};
    if (s < e) {
        int cA0 = csr_col[s + 0  + sub];
        int cA1 = csr_col[s + 4  + sub];
        int cA2 = csr_col[s + 8  + sub];
        int cA3 = csr_col[s + 12 + sub];
        uint4 vA0 = *(const uint4*)(hp + (size_t)cA0 * HALF_CH + l16 * 8);
        uint4 vA1 = *(const uint4*)(hp + (size_t)cA1 * HALF_CH + l16 * 8);
        uint4 vA2 = *(const uint4*)(hp + (size_t)cA2 * HALF_CH + l16 * 8);
        uint4 vA3 = *(const uint4*)(hp + (size_t)cA3 * HALF_CH + l16 * 8);
        int cB0 = csr_col[s + 16 + sub];   // slack-safe beyond e (never dereferenced then)
        int cB1 = csr_col[s + 20 + sub];
        int cB2 = csr_col[s + 24 + sub];
        int cB3 = csr_col[s + 28 + sub];
        int p = s;
        while (p + 16 < e) {
            uint4 vB0 = *(const uint4*)(hp + (size_t)cB0 * HALF_CH + l16 * 8);
            uint4 vB1 = *(const uint4*)(hp + (size_t)cB1 * HALF_CH + l16 * 8);
            uint4 vB2 = *(const uint4*)(hp + (size_t)cB2 * HALF_CH + l16 * 8);
            uint4 vB3 = *(const uint4*)(hp + (size_t)cB3 * HALF_CH + l16 * 8);
            int pn = p + 32;
            int cC0 = csr_col[pn + 0  + sub];   // prefetch 2 groups ahead (slack-safe)
            int cC1 = csr_col[pn + 4  + sub];
            int cC2 = csr_col[pn + 8  + sub];
            int cC3 = csr_col[pn + 12 + sub];
            acc[0] += lo16(vA0.x) + lo16(vA1.x) + lo16(vA2.x) + lo16(vA3.x);
            acc[1] += hi16(vA0.x) + hi16(vA1.x) + hi16(vA2.x) + hi16(vA3.x);
            acc[2] += lo16(vA0.y) + lo16(vA1.y) + lo16(vA2.y) + lo16(vA3.y);
            acc[3] += hi16(vA0.y) + hi16(vA1.y) + hi16(vA2.y) + hi16(vA3.y);
            acc[4] += lo16(vA0.z) + lo16(vA1.z) + lo16(vA2.z) + lo16(vA3.z);
            acc[5] += hi16(vA0.z) + hi16(vA1.z) + hi16(vA2.z) + hi16(vA3.z);
            acc[6] += lo16(vA0.w) + lo16(vA1.w) + lo16(vA2.w) + lo16(vA3.w);
            acc[7] += hi16(vA0.w) + hi16(vA1.w) + hi16(vA2.w) + hi16(vA3.w);
            vA0 = vB0; vA1 = vB1; vA2 = vB2; vA3 = vB3;
            cB0 = cC0; cB1 = cC1; cB2 = cC2; cB3 = cC3;
            p += 16;
        }
        acc[0] += lo16(vA0.x) + lo16(vA1.x) + lo16(vA2.x) + lo16(vA3.x);
        acc[1] += hi16(vA0.x) + hi16(vA1.x) + hi16(vA2.x) + hi16(vA3.x);
        acc[2] += lo16(vA0.y) + lo16(vA1.y) + lo16(vA2.y) + lo16(vA3.y);
        acc[3] += hi16(vA0.y) + hi16(vA1.y) + hi16(vA2.y) + hi16(vA3.y);
        acc[4] += lo16(vA0.z) + lo16(vA1.z) + lo16(vA2.z) + lo16(vA3.z);
        acc[5] += hi16(vA0.z) + hi16(vA1.z) + hi16(vA2.z) + hi16(vA3.z);
        acc[6] += lo16(vA0.w) + lo16(vA1.w) + lo16(vA2.w) + lo16(vA3.w);
        acc[7] += hi16(vA0.w) + hi16(vA1.w) + hi16(vA2.w) + hi16(vA3.w);
    }
    #pragma unroll
    for (int k = 0; k < 8; k++) {
        acc[k] += __shfl_xor(acc[k], 16, 64);
        acc[k] += __shfl_xor(acc[k], 32, 64);
    }
    if (sub != 0) return;

    float di = dinv[node];
    float y[8];
    #pragma unroll
    for (int k = 0; k < 8; k++) y[k] = di * acc[k];

    size_t pbase = (size_t)plane * pstride + (size_t)node * HALF_CH + l16 * 8;
    size_t padrow = (size_t)plane * pstride + (size_t)n * HALF_CH + l16 * 8;
    if (yb_out) {
        ushort4 o0, o1;
        o0.x = f2b(di * y[0]); o0.y = f2b(di * y[1]); o0.z = f2b(di * y[2]); o0.w = f2b(di * y[3]);
        o1.x = f2b(di * y[4]); o1.y = f2b(di * y[5]); o1.z = f2b(di * y[6]); o1.w = f2b(di * y[7]);
        *(ushort4*)(yb_out + pbase) = o0;
        *(ushort4*)(yb_out + pbase + 4) = o1;
        if (node == 0) {
            ushort4 z = {0, 0, 0, 0};
            *(ushort4*)(yb_out + padrow) = z;
            *(ushort4*)(yb_out + padrow + 4) = z;
        }
    }
    if (prev_b) {
        float wk = wts[widx];
        float sqn = sq[node];
        ushort4 p0 = *(const ushort4*)(prev_b + pbase);
        ushort4 p1 = *(const ushort4*)(prev_b + pbase + 4);
        float o[8];
        o[0] = b2f(p0.x) * sqn + wk * y[0];
        o[1] = b2f(p0.y) * sqn + wk * y[1];
        o[2] = b2f(p0.z) * sqn + wk * y[2];
        o[3] = b2f(p0.w) * sqn + wk * y[3];
        o[4] = b2f(p1.x) * sqn + wk * y[4];
        o[5] = b2f(p1.y) * sqn + wk * y[5];
        o[6] = b2f(p1.z) * sqn + wk * y[6];
        o[7] = b2f(p1.w) * sqn + wk * y[7];
        if (axpy_out) {
            size_t fbase = (size_t)node * OUT_CH + plane * HALF_CH + l16 * 8;
            float4 f0 = {o[0], o[1], o[2], o[3]};
            float4 f1 = {o[4], o[5], o[6], o[7]};
            *(float4*)(axpy_out + fbase) = f0;
            *(float4*)(axpy_out + fbase + 4) = f1;
        }
        if (axpyb_out) {
            ushort4 b0, b1;
            b0.x = f2b(di * o[0]); b0.y = f2b(di * o[1]); b0.z = f2b(di * o[2]); b0.w = f2b(di * o[3]);
            b1.x = f2b(di * o[4]); b1.y = f2b(di * o[5]); b1.z = f2b(di * o[6]); b1.w = f2b(di * o[7]);
            *(ushort4*)(axpyb_out + pbase) = b0;
            *(ushort4*)(axpyb_out + pbase + 4) = b1;
            if (node == 0) {
                ushort4 z = {0, 0, 0, 0};
                *(ushort4*)(axpyb_out + padrow) = z;
                *(ushort4*)(axpyb_out + padrow + 4) = z;
            }
        }
    }
}

// ---------------- PROBE: 4 gather-sweeps (= 2.0 real spmm passes), scratch output --------
// Measurement-only dispatch, launched LAST (reads h0b/out1b, writes scratch). Different
// data each sweep (src x plane) so no sweep can be CSE'd away. Its counter row gives the
// first direct occupancy/VALUBusy/FETCH observation of the gather loop; dur/2 = per-pass.
__global__ __launch_bounds__(256) void spmm_probe(const unsigned short* __restrict__ hb0,
                                                  const unsigned short* __restrict__ hb1,
                                                  const int2* __restrict__ seg,
                                                  const unsigned short* __restrict__ csr_col,
                                                  float* __restrict__ scratch, int n) {
    int node = blockIdx.x * 4 + (threadIdx.x >> 6);
    int lane = threadIdx.x & 63;
    if (node >= n) return;
    int sub = lane >> 4, l16 = lane & 15;
    size_t pstride = (size_t)(n + 1) * HALF_CH;
    int2 se = seg[node];
    float acc[8] = {0.f, 0.f, 0.f, 0.f, 0.f, 0.f, 0.f, 0.f};
    for (int src = 0; src < 2; src++) {
        const unsigned short* hbase = src ? hb1 : hb0;
        for (int plane = 0; plane < 2; plane++) {
            const unsigned short* hp = hbase + (size_t)plane * pstride;
            int s = se.x, e = se.y;
            if (s >= e) continue;
            int c0 = csr_col[s + 0  + sub];
            int c1 = csr_col[s + 4  + sub];
            int c2 = csr_col[s + 8  + sub];
            int c3 = csr_col[s + 12 + sub];
            int p = s;
            while (true) {
                int pn = p + 16;
                int n0c = csr_col[pn + 0  + sub];
                int n1c = csr_col[pn + 4  + sub];
                int n2c = csr_col[pn + 8  + sub];
                int n3c = csr_col[pn + 12 + sub];
                uint4 v0 = *(const uint4*)(hp + (size_t)c0 * HALF_CH + l16 * 8);
                uint4 v1 = *(const uint4*)(hp + (size_t)c1 * HALF_CH + l16 * 8);
                uint4 v2 = *(const uint4*)(hp + (size_t)c2 * HALF_CH + l16 * 8);
                uint4 v3 = *(const uint4*)(hp + (size_t)c3 * HALF_CH + l16 * 8);
                acc[0] += lo16(v0.x) + lo16(v1.x) + lo16(v2.x) + lo16(v3.x);
                acc[1] += hi16(v0.x) + hi16(v1.x) + hi16(v2.x) + hi16(v3.x);
                acc[2] += lo16(v0.y) + lo16(v1.y) + lo16(v2.y) + lo16(v3.y);
                acc[3] += hi16(v0.y) + hi16(v1.y) + hi16(v2.y) + hi16(v3.y);
                acc[4] += lo16(v0.z) + lo16(v1.z) + lo16(v2.z) + lo16(v3.z);
                acc[5] += hi16(v0.z) + hi16(v1.z) + hi16(v2.z) + hi16(v3.z);
                acc[6] += lo16(v0.w) + lo16(v1.w) + lo16(v2.w) + lo16(v3.w);
                acc[7] += hi16(v0.w) + hi16(v1.w) + hi16(v2.w) + hi16(v3.w);
                c0 = n0c; c1 = n1c; c2 = n2c; c3 = n3c; p = pn;
                if (p >= e) break;
            }
        }
    }
    #pragma unroll
    for (int k = 0; k < 8; k++) {
        acc[k] += __shfl_xor(acc[k], 16, 64);
        acc[k] += __shfl_xor(acc[k], 32, 64);
    }
    if (sub != 0) return;
    float4 f0 = {acc[0], acc[1], acc[2], acc[3]};
    float4 f1 = {acc[4], acc[5], acc[6], acc[7]};
    *(float4*)(scratch + (size_t)node * HALF_CH + l16 * 8) = f0;
    *(float4*)(scratch + (size_t)node * HALF_CH + l16 * 8 + 4) = f1;
}

extern "C" void kernel_launch(void* const* d_in, const int* in_sizes, int n_in,
                              void* d_out, int out_size, void* d_ws, size_t ws_size,
                              hipStream_t stream) {
    const float* x     = (const float*)d_in[0];
    const int*   ei    = (const int*)d_in[1];   // [2, E]
    const float* lin_w = (const float*)d_in[2]; // [OUT_CH, IN_CH]
    const float* lin_b = (const float*)d_in[3]; // [OUT_CH]
    const float* wts   = (const float*)d_in[4]; // [K]
    float* out = (float*)d_out;

    char* ws = (char*)d_ws;
    size_t off = 0;
    auto alloc = [&](size_t bytes) -> void* {
        void* p = ws + off;
        off += (bytes + 255) & ~(size_t)255;
        return p;
    };
    int*   cnt      = (int*)  alloc((size_t)HBLK * N_NODES * 4);  // [HBLK][N] counts->bases
    unsigned short* rank = (unsigned short*)alloc((size_t)E_EDGES * 2);
    int2*  pd       = (int2*) alloc((size_t)N_NODES * 8);
    int*   pads     = (int*)  alloc((size_t)N_NODES * 4);
    int*   rowstart = (int*)  alloc((size_t)N_NODES * 4);
    int2*  seg      = (int2*) alloc((size_t)N_NODES * 8);
    float* dinv     = (float*)alloc(N_NODES * 4);
    float* sq       = (float*)alloc(N_NODES * 4);
    unsigned short* csr_col = (unsigned short*)alloc((size_t)CSR_CAP * 2);  // u16 cols
    float* h0f      = (float*)alloc((size_t)2 * N_NODES * HALF_CH * 4);   // raw f32 GEMM out
    unsigned short* h0b   = (unsigned short*)alloc((size_t)2 * (N_NODES + 1) * HALF_CH * 2);
    unsigned short* out1b = (unsigned short*)alloc((size_t)2 * (N_NODES + 1) * HALF_CH * 2);
    unsigned short* t2b   = (unsigned short*)alloc((size_t)2 * (N_NODES + 1) * HALF_CH * 2);
    float* scratch  = (float*)alloc((size_t)N_NODES * HALF_CH * 4);       // probe output

    const int* row = ei;
    const int* col = ei + E_EDGES;

    // GEMM (independent of graph) || histogram/rank — overlapped
    gemm_hist<<<G_GEMM + HBLK, 256, 0, stream>>>(x, lin_w, lin_b, h0f, row, cnt, rank);

    alloc_a<<<(N_NODES + 3) / 4, 256, 0, stream>>>(cnt, pd, dinv, sq, pads, N_NODES);
    scan_pads<<<1, 1024, 0, stream>>>(pads, rowstart, N_NODES);
    alloc_b<<<(N_NODES + 3) / 4, 256, 0, stream>>>(rowstart, pd, seg, csr_col, N_NODES);

    // CSR scatter || h0f -> dinv-pre-scaled bf16 h0b
    scatter_scale<<<HBLK + G_SCALE, 256, 0, stream>>>(row, col, cnt, rowstart, rank,
                                                      csr_col, h0f, dinv, h0b);

    int sgrid = 2 * ((N_NODES + 3) / 4); // plane = bid&1, 4 nodes/block
    // out1b = dinv*(h0 + w0 * spmm(h0)), h0 reconstructed from h0b
    spmm_kernel<<<sgrid, 256, 0, stream>>>(h0b, seg, csr_col, dinv, sq, h0b,
                                           wts, 0, nullptr, nullptr, out1b, N_NODES);
    // t2b = dinv*spmm(out1)
    spmm_kernel<<<sgrid, 256, 0, stream>>>(out1b, seg, csr_col, dinv, sq, nullptr,
                                           wts, 0, t2b, nullptr, nullptr, N_NODES);
    // out = out1 + w1 * spmm(t2), out1 reconstructed from out1b  (fp32 final)
    spmm_kernel<<<sgrid, 256, 0, stream>>>(t2b, seg, csr_col, dinv, sq, out1b,
                                           wts, 1, nullptr, out, nullptr, N_NODES);

    // MEASUREMENT probe (reads h0b/out1b, writes scratch; no consumer — remove next round)
    spmm_probe<<<(N_NODES + 3) / 4, 256, 0, stream>>>(h0b, out1b, seg, csr_col,
                                                      scratch, N_NODES);
}

// Round 9
// 193.292 us; speedup vs baseline: 1.3213x; 1.3213x over previous
//
#include <hip/hip_runtime.h>

#define N_NODES 10000
#define E_EDGES 640000
#define IN_CH   512
#define OUT_CH  256
#define HALF_CH 128
#define CSR_CAP (E_EDGES + 16 * N_NODES + 128)  // pad-16 capacity + prefetch slack (u16 entries)
#define G_GEMM_X 157                            // ceil(10000/64)
#define G_GEMM  (G_GEMM_X * 2)                  // x2 planes
#define HBLK    125                             // histogram/scatter chunks
#define EPB     5120                            // edges per chunk: 125*5120 = 640000
#define G_SCALE 2500                            // scale blocks: 4 nodes each
#define G_CONVX 2500                            // x-convert blocks (2048 f32 each)
#define G_CONVW 64                              // w-convert blocks
#define G_ALLOCA 2500                           // alloc_a blocks (4 rows each)

typedef short bf16x8 __attribute__((ext_vector_type(8)));
typedef float f32x4  __attribute__((ext_vector_type(4)));

__device__ __forceinline__ unsigned short f2b(float f) {
    unsigned int u = __float_as_uint(f);
    return (unsigned short)((u + 0x7FFFu + ((u >> 16) & 1u)) >> 16);
}
__device__ __forceinline__ float lo16(unsigned int u) { return __uint_as_float(u << 16); }
__device__ __forceinline__ float hi16(unsigned int u) { return __uint_as_float(u & 0xFFFF0000u); }
__device__ __forceinline__ float b2f(unsigned short u) { return __uint_as_float(((unsigned int)u) << 16); }

// ---------------- conv (x,w -> bf16, hoisted out of GEMM loop) || LDS-hist rank ---------
// Identical f2b rounding as the old in-loop conversion -> bit-identical GEMM inputs.
__global__ __launch_bounds__(256) void conv_hist(const float* __restrict__ x,
                                                 const float* __restrict__ w,
                                                 unsigned short* __restrict__ xb,
                                                 unsigned short* __restrict__ wb,
                                                 const int* __restrict__ row,
                                                 int* __restrict__ cnt,          // [HBLK][N]
                                                 unsigned short* __restrict__ rank) {
    int bid = blockIdx.x;
    int tid = threadIdx.x;
    if (bid < HBLK) {
        // ---- hist path ----
        __shared__ int hist[N_NODES];
        for (int i = tid; i < N_NODES; i += 256) hist[i] = 0;
        __syncthreads();
        int ebase = bid * EPB;
        for (int i = tid; i < EPB; i += 256) {
            int r = row[ebase + i];
            rank[ebase + i] = (unsigned short)atomicAdd(&hist[r], 1);
        }
        __syncthreads();
        int* cb = cnt + (size_t)bid * N_NODES;
        for (int i = tid; i < N_NODES; i += 256) cb[i] = hist[i];
        return;
    }
    // ---- convert path: 8 f32 -> 8 bf16 per thread ----
    int u = bid - HBLK;
    const float* src;
    unsigned short* dst;
    size_t base;
    if (u < G_CONVX) { src = x;  dst = xb; base = (size_t)u * 2048 + tid * 8; }
    else             { src = w;  dst = wb; base = (size_t)(u - G_CONVX) * 2048 + tid * 8; }
    float4 a = *(const float4*)(src + base);
    float4 b = *(const float4*)(src + base + 4);
    ushort4 lo, hi;
    lo.x = f2b(a.x); lo.y = f2b(a.y); lo.z = f2b(a.z); lo.w = f2b(a.w);
    hi.x = f2b(b.x); hi.y = f2b(b.y); hi.z = f2b(b.z); hi.w = f2b(b.w);
    *(ushort4*)(dst + base) = lo;
    *(ushort4*)(dst + base + 4) = hi;
}

// ---------------- GEMM (bf16 inputs, copy-only staging) || alloc_a ----------------------
// GEMM: raw f32 out (no dinv dep). alloc_a: shuffle-scan 125 partials -> degree/pad/
// dinv/sq/pd/pads + local per-block bases in place. alloc_a's uncoalesced reads hide
// under GEMM compute in the same dispatch.
__global__ __launch_bounds__(256) void gemm_alloca(const unsigned short* __restrict__ xb,
                                                   const unsigned short* __restrict__ wb,
                                                   const float* __restrict__ bias,
                                                   float* __restrict__ h0f,    // [2][N][128] f32
                                                   int* __restrict__ cnt,      // [HBLK][N]
                                                   int2* __restrict__ pd,
                                                   float* __restrict__ dinv, float* __restrict__ sq,
                                                   int* __restrict__ pads, int n) {
    __shared__ unsigned short As[64][72];
    __shared__ unsigned short Bs[128][72];
    int bid = blockIdx.x;
    int tid = threadIdx.x;
    if (bid >= G_GEMM) {
        // ---- alloc_a path ----
        int r = (bid - G_GEMM) * 4 + (tid >> 6);
        int lane = tid & 63;
        if (r >= n) return;
        int v0 = cnt[(size_t)lane * N_NODES + r];                               // b = lane
        int v1 = (lane < HBLK - 64) ? cnt[(size_t)(64 + lane) * N_NODES + r] : 0;
        int s0 = v0, s1 = v1;                                // inclusive scans over b
        #pragma unroll
        for (int off = 1; off < 64; off <<= 1) {
            int t0 = __shfl_up(s0, off, 64);
            int t1 = __shfl_up(s1, off, 64);
            if (lane >= off) { s0 += t0; s1 += t1; }
        }
        int tot0 = __shfl(s0, 63, 64);
        int d = tot0 + __shfl(s1, 63, 64);
        int pad = (d + 15) & ~15;
        cnt[(size_t)lane * N_NODES + r] = s0 - v0;           // local exclusive base, b=lane
        if (lane < HBLK - 64) cnt[(size_t)(64 + lane) * N_NODES + r] = tot0 + s1 - v1;
        if (lane == 0) {
            dinv[r] = (d > 0) ? rsqrtf((float)d) : 0.0f;
            sq[r]   = (d > 0) ? sqrtf((float)d) : 0.0f;
            pd[r] = make_int2(d, pad);
            pads[r] = pad;
        }
        return;
    }
    // ---- gemm path: staging is now pure uint4 copies (no f2b in loop) ----
    int bx = bid % G_GEMM_X;
    int plane = bid / G_GEMM_X;
    int wave = tid >> 6, lane = tid & 63, quad = lane >> 4, l16 = lane & 15;
    int row0 = bx * 64;
    int n0 = plane * 128;
    float* h0f_p = h0f + (size_t)plane * N_NODES * HALF_CH;

    int ar = tid >> 2;
    int aseg = (tid & 3) * 16;
    int br = tid >> 1;
    int bseg = (tid & 1) * 32;

    f32x4 acc[8] = {};
    for (int k0 = 0; k0 < IN_CH; k0 += 64) {
        {
            int gr = row0 + ar;
            if (gr < N_NODES) {
                const uint4* src = (const uint4*)(xb + (size_t)gr * IN_CH + k0 + aseg);
                *(uint4*)&As[ar][aseg]     = src[0];
                *(uint4*)&As[ar][aseg + 8] = src[1];
            } else {
                uint4 z = {0, 0, 0, 0};
                *(uint4*)&As[ar][aseg]     = z;
                *(uint4*)&As[ar][aseg + 8] = z;
            }
        }
        {
            const uint4* src = (const uint4*)(wb + (size_t)(n0 + br) * IN_CH + k0 + bseg);
            *(uint4*)&Bs[br][bseg]      = src[0];
            *(uint4*)&Bs[br][bseg + 8]  = src[1];
            *(uint4*)&Bs[br][bseg + 16] = src[2];
            *(uint4*)&Bs[br][bseg + 24] = src[3];
        }
        __syncthreads();
        #pragma unroll
        for (int kk = 0; kk < 2; kk++) {
            bf16x8 a = *(const bf16x8*)&As[wave * 16 + l16][kk * 32 + quad * 8];
            #pragma unroll
            for (int t = 0; t < 8; t++) {
                bf16x8 b = *(const bf16x8*)&Bs[t * 16 + l16][kk * 32 + quad * 8];
                acc[t] = __builtin_amdgcn_mfma_f32_16x16x32_bf16(a, b, acc[t], 0, 0, 0);
            }
        }
        __syncthreads();
    }
    #pragma unroll
    for (int t = 0; t < 8; t++) {
        int lcol = t * 16 + l16;
        float bv = bias[n0 + lcol];
        #pragma unroll
        for (int r = 0; r < 4; r++) {
            int grow = row0 + wave * 16 + quad * 4 + r;
            if (grow < N_NODES)
                h0f_p[(size_t)grow * HALF_CH + lcol] = acc[t][r] + bv;
        }
    }
}

// ---------------- scan_pads: single-block exclusive scan of 10000 pads ----------------
__global__ __launch_bounds__(1024) void scan_pads(const int* __restrict__ pads,
                                                  int* __restrict__ rowstart, int n) {
    __shared__ int ls[1024];
    int t = threadIdx.x;
    int base = t * 10;                  // 1000 threads x 10 elements covers 10000
    int loc[10];
    int sum = 0;
    if (base < n) {
        #pragma unroll
        for (int i = 0; i < 10; i++) { loc[i] = pads[base + i]; sum += loc[i]; }
    }
    ls[t] = sum;
    __syncthreads();
    for (int off = 1; off < 1024; off <<= 1) {
        int v = (t >= off) ? ls[t - off] : 0;
        __syncthreads();
        ls[t] += v;
        __syncthreads();
    }
    if (base < n) {
        int run = ls[t] - sum;          // exclusive block prefix
        #pragma unroll
        for (int i = 0; i < 10; i++) { rowstart[base + i] = run; run += loc[i]; }
    }
}

// ---------------- alloc_b: wave/row — seg + sentinels (csr u16) ----------------
__global__ __launch_bounds__(256) void alloc_b(const int* __restrict__ rowstart,
                                               const int2* __restrict__ pd,
                                               int2* __restrict__ seg,
                                               unsigned short* __restrict__ csr_col, int n) {
    int r = blockIdx.x * 4 + (threadIdx.x >> 6);
    int lane = threadIdx.x & 63;
    if (r >= n) return;
    int s = rowstart[r];
    int2 pd_ = pd[r];
    if (lane == 0) seg[r] = make_int2(s, s + pd_.y);
    int j = pd_.x + lane;               // sentinels: [d, pad), <= 15 slots
    if (j < pd_.y) csr_col[s + j] = (unsigned short)N_NODES;
}

// ---------------- scatter (LDS-staged bases, u16 stores) || scale h0f -> bf16 h0b --------
__global__ __launch_bounds__(256) void scatter_scale(const int* __restrict__ row,
                                                     const int* __restrict__ col,
                                                     const int* __restrict__ base,   // [HBLK][N]
                                                     const int* __restrict__ rowstart,
                                                     const unsigned short* __restrict__ rank,
                                                     unsigned short* __restrict__ csr_col,
                                                     const float* __restrict__ h0f,  // [2][N][128]
                                                     const float* __restrict__ dinv,
                                                     unsigned short* __restrict__ h0b) {
    int bid = blockIdx.x;
    int tid = threadIdx.x;
    size_t pstride = (size_t)(N_NODES + 1) * HALF_CH;
    if (bid < HBLK) {
        // ---- scatter path: stage absolutized base row into 40KB LDS, then scatter ----
        __shared__ int bs[N_NODES];
        const int4* cb4 = (const int4*)(base + (size_t)bid * N_NODES);
        const int4* rs4 = (const int4*)rowstart;
        for (int i = tid; i < N_NODES / 4; i += 256) {   // 2500 int4, coalesced
            int4 c = cb4[i];
            int4 r = rs4[i];
            int4 o;
            o.x = c.x + r.x; o.y = c.y + r.y; o.z = c.z + r.z; o.w = c.w + r.w;
            ((int4*)bs)[i] = o;
        }
        __syncthreads();
        int ebase = bid * EPB;
        for (int i = tid; i < EPB; i += 256) {
            int e = ebase + i;
            int p = bs[row[e]] + (int)rank[e];
            csr_col[p] = (unsigned short)col[e];
        }
        return;
    }
    // ---- scale path: 4 nodes/block, both planes; single rounding f32 -> bf16 ----
    int idx = bid - HBLK;
    int node = idx * 4 + (tid >> 6);
    int lane = tid & 63;
    float di = dinv[node];
    #pragma unroll
    for (int plane = 0; plane < 2; plane++) {
        const float2* src = (const float2*)(h0f + (size_t)plane * N_NODES * HALF_CH
                                            + (size_t)node * HALF_CH);
        float2 v = src[lane];
        unsigned int o = (unsigned int)f2b(v.x * di) | ((unsigned int)f2b(v.y * di) << 16);
        ((unsigned int*)(h0b + (size_t)plane * pstride + (size_t)node * HALF_CH))[lane] = o;
    }
    // zero the pad rows (sentinel gather target) — first scale block only
    if (idx == 0 && tid < 128) {
        int plane = tid >> 6;
        ((unsigned int*)(h0b + (size_t)plane * pstride + (size_t)N_NODES * HALF_CH))[tid & 63] = 0u;
    }
}

// ---------------- SpMM: XCD-plane-partitioned, double-buffered gathers (csr u16) --------
__global__ __launch_bounds__(256) void spmm_kernel(const unsigned short* __restrict__ hb,
                                                   const int2* __restrict__ seg,
                                                   const unsigned short* __restrict__ csr_col,
                                                   const float* __restrict__ dinv,
                                                   const float* __restrict__ sq,
                                                   const unsigned short* __restrict__ prev_b,
                                                   const float* __restrict__ wts, int widx,
                                                   unsigned short* __restrict__ yb_out,
                                                   float* __restrict__ axpy_out,
                                                   unsigned short* __restrict__ axpyb_out,
                                                   int n) {
    int plane = blockIdx.x & 1;
    int node = (blockIdx.x >> 1) * 4 + (threadIdx.x >> 6);
    int lane = threadIdx.x & 63;
    if (node >= n) return;
    int sub = lane >> 4, l16 = lane & 15;
    size_t pstride = (size_t)(n + 1) * HALF_CH;
    const unsigned short* hp = hb + (size_t)plane * pstride;

    int2 se = seg[node];
    int s = se.x, e = se.y;
    float acc[8] = {0.f, 0.f, 0.f, 0.f, 0.f, 0.f, 0.f, 0.f};
    if (s < e) {
        int cA0 = csr_col[s + 0  + sub];
        int cA1 = csr_col[s + 4  + sub];
        int cA2 = csr_col[s + 8  + sub];
        int cA3 = csr_col[s + 12 + sub];
        uint4 vA0 = *(const uint4*)(hp + (size_t)cA0 * HALF_CH + l16 * 8);
        uint4 vA1 = *(const uint4*)(hp + (size_t)cA1 * HALF_CH + l16 * 8);
        uint4 vA2 = *(const uint4*)(hp + (size_t)cA2 * HALF_CH + l16 * 8);
        uint4 vA3 = *(const uint4*)(hp + (size_t)cA3 * HALF_CH + l16 * 8);
        int cB0 = csr_col[s + 16 + sub];   // slack-safe beyond e (never dereferenced then)
        int cB1 = csr_col[s + 20 + sub];
        int cB2 = csr_col[s + 24 + sub];
        int cB3 = csr_col[s + 28 + sub];
        int p = s;
        while (p + 16 < e) {
            uint4 vB0 = *(const uint4*)(hp + (size_t)cB0 * HALF_CH + l16 * 8);
            uint4 vB1 = *(const uint4*)(hp + (size_t)cB1 * HALF_CH + l16 * 8);
            uint4 vB2 = *(const uint4*)(hp + (size_t)cB2 * HALF_CH + l16 * 8);
            uint4 vB3 = *(const uint4*)(hp + (size_t)cB3 * HALF_CH + l16 * 8);
            int pn = p + 32;
            int cC0 = csr_col[pn + 0  + sub];   // prefetch 2 groups ahead (slack-safe)
            int cC1 = csr_col[pn + 4  + sub];
            int cC2 = csr_col[pn + 8  + sub];
            int cC3 = csr_col[pn + 12 + sub];
            acc[0] += lo16(vA0.x) + lo16(vA1.x) + lo16(vA2.x) + lo16(vA3.x);
            acc[1] += hi16(vA0.x) + hi16(vA1.x) + hi16(vA2.x) + hi16(vA3.x);
            acc[2] += lo16(vA0.y) + lo16(vA1.y) + lo16(vA2.y) + lo16(vA3.y);
            acc[3] += hi16(vA0.y) + hi16(vA1.y) + hi16(vA2.y) + hi16(vA3.y);
            acc[4] += lo16(vA0.z) + lo16(vA1.z) + lo16(vA2.z) + lo16(vA3.z);
            acc[5] += hi16(vA0.z) + hi16(vA1.z) + hi16(vA2.z) + hi16(vA3.z);
            acc[6] += lo16(vA0.w) + lo16(vA1.w) + lo16(vA2.w) + lo16(vA3.w);
            acc[7] += hi16(vA0.w) + hi16(vA1.w) + hi16(vA2.w) + hi16(vA3.w);
            vA0 = vB0; vA1 = vB1; vA2 = vB2; vA3 = vB3;
            cB0 = cC0; cB1 = cC1; cB2 = cC2; cB3 = cC3;
            p += 16;
        }
        acc[0] += lo16(vA0.x) + lo16(vA1.x) + lo16(vA2.x) + lo16(vA3.x);
        acc[1] += hi16(vA0.x) + hi16(vA1.x) + hi16(vA2.x) + hi16(vA3.x);
        acc[2] += lo16(vA0.y) + lo16(vA1.y) + lo16(vA2.y) + lo16(vA3.y);
        acc[3] += hi16(vA0.y) + hi16(vA1.y) + hi16(vA2.y) + hi16(vA3.y);
        acc[4] += lo16(vA0.z) + lo16(vA1.z) + lo16(vA2.z) + lo16(vA3.z);
        acc[5] += hi16(vA0.z) + hi16(vA1.z) + hi16(vA2.z) + hi16(vA3.z);
        acc[6] += lo16(vA0.w) + lo16(vA1.w) + lo16(vA2.w) + lo16(vA3.w);
        acc[7] += hi16(vA0.w) + hi16(vA1.w) + hi16(vA2.w) + hi16(vA3.w);
    }
    #pragma unroll
    for (int k = 0; k < 8; k++) {
        acc[k] += __shfl_xor(acc[k], 16, 64);
        acc[k] += __shfl_xor(acc[k], 32, 64);
    }
    if (sub != 0) return;

    float di = dinv[node];
    float y[8];
    #pragma unroll
    for (int k = 0; k < 8; k++) y[k] = di * acc[k];

    size_t pbase = (size_t)plane * pstride + (size_t)node * HALF_CH + l16 * 8;
    size_t padrow = (size_t)plane * pstride + (size_t)n * HALF_CH + l16 * 8;
    if (yb_out) {
        ushort4 o0, o1;
        o0.x = f2b(di * y[0]); o0.y = f2b(di * y[1]); o0.z = f2b(di * y[2]); o0.w = f2b(di * y[3]);
        o1.x = f2b(di * y[4]); o1.y = f2b(di * y[5]); o1.z = f2b(di * y[6]); o1.w = f2b(di * y[7]);
        *(ushort4*)(yb_out + pbase) = o0;
        *(ushort4*)(yb_out + pbase + 4) = o1;
        if (node == 0) {
            ushort4 z = {0, 0, 0, 0};
            *(ushort4*)(yb_out + padrow) = z;
            *(ushort4*)(yb_out + padrow + 4) = z;
        }
    }
    if (prev_b) {
        float wk = wts[widx];
        float sqn = sq[node];
        ushort4 p0 = *(const ushort4*)(prev_b + pbase);
        ushort4 p1 = *(const ushort4*)(prev_b + pbase + 4);
        float o[8];
        o[0] = b2f(p0.x) * sqn + wk * y[0];
        o[1] = b2f(p0.y) * sqn + wk * y[1];
        o[2] = b2f(p0.z) * sqn + wk * y[2];
        o[3] = b2f(p0.w) * sqn + wk * y[3];
        o[4] = b2f(p1.x) * sqn + wk * y[4];
        o[5] = b2f(p1.y) * sqn + wk * y[5];
        o[6] = b2f(p1.z) * sqn + wk * y[6];
        o[7] = b2f(p1.w) * sqn + wk * y[7];
        if (axpy_out) {
            size_t fbase = (size_t)node * OUT_CH + plane * HALF_CH + l16 * 8;
            float4 f0 = {o[0], o[1], o[2], o[3]};
            float4 f1 = {o[4], o[5], o[6], o[7]};
            *(float4*)(axpy_out + fbase) = f0;
            *(float4*)(axpy_out + fbase + 4) = f1;
        }
        if (axpyb_out) {
            ushort4 b0, b1;
            b0.x = f2b(di * o[0]); b0.y = f2b(di * o[1]); b0.z = f2b(di * o[2]); b0.w = f2b(di * o[3]);
            b1.x = f2b(di * o[4]); b1.y = f2b(di * o[5]); b1.z = f2b(di * o[6]); b1.w = f2b(di * o[7]);
            *(ushort4*)(axpyb_out + pbase) = b0;
            *(ushort4*)(axpyb_out + pbase + 4) = b1;
            if (node == 0) {
                ushort4 z = {0, 0, 0, 0};
                *(ushort4*)(axpyb_out + padrow) = z;
                *(ushort4*)(axpyb_out + padrow + 4) = z;
            }
        }
    }
}

extern "C" void kernel_launch(void* const* d_in, const int* in_sizes, int n_in,
                              void* d_out, int out_size, void* d_ws, size_t ws_size,
                              hipStream_t stream) {
    const float* x     = (const float*)d_in[0];
    const int*   ei    = (const int*)d_in[1];   // [2, E]
    const float* lin_w = (const float*)d_in[2]; // [OUT_CH, IN_CH]
    const float* lin_b = (const float*)d_in[3]; // [OUT_CH]
    const float* wts   = (const float*)d_in[4]; // [K]
    float* out = (float*)d_out;

    char* ws = (char*)d_ws;
    size_t off = 0;
    auto alloc = [&](size_t bytes) -> void* {
        void* p = ws + off;
        off += (bytes + 255) & ~(size_t)255;
        return p;
    };
    int*   cnt      = (int*)  alloc((size_t)HBLK * N_NODES * 4);  // [HBLK][N] counts->bases
    unsigned short* rank = (unsigned short*)alloc((size_t)E_EDGES * 2);
    int2*  pd       = (int2*) alloc((size_t)N_NODES * 8);
    int*   pads     = (int*)  alloc((size_t)N_NODES * 4);
    int*   rowstart = (int*)  alloc((size_t)N_NODES * 4);
    int2*  seg      = (int2*) alloc((size_t)N_NODES * 8);
    float* dinv     = (float*)alloc(N_NODES * 4);
    float* sq       = (float*)alloc(N_NODES * 4);
    unsigned short* csr_col = (unsigned short*)alloc((size_t)CSR_CAP * 2);  // u16 cols
    unsigned short* xb = (unsigned short*)alloc((size_t)N_NODES * IN_CH * 2);  // bf16 x
    unsigned short* wb = (unsigned short*)alloc((size_t)OUT_CH * IN_CH * 2);   // bf16 w
    float* h0f      = (float*)alloc((size_t)2 * N_NODES * HALF_CH * 4);   // raw f32 GEMM out
    unsigned short* h0b   = (unsigned short*)alloc((size_t)2 * (N_NODES + 1) * HALF_CH * 2);
    unsigned short* out1b = (unsigned short*)alloc((size_t)2 * (N_NODES + 1) * HALF_CH * 2);
    unsigned short* t2b   = (unsigned short*)alloc((size_t)2 * (N_NODES + 1) * HALF_CH * 2);

    const int* row = ei;
    const int* col = ei + E_EDGES;

    // hist || x/w bf16 conversion (all independent)
    conv_hist<<<HBLK + G_CONVX + G_CONVW, 256, 0, stream>>>(x, lin_w, xb, wb,
                                                            row, cnt, rank);
    // GEMM (bf16, copy-only staging) || alloc_a
    gemm_alloca<<<G_GEMM + G_ALLOCA, 256, 0, stream>>>(xb, wb, lin_b, h0f, cnt,
                                                       pd, dinv, sq, pads, N_NODES);
    scan_pads<<<1, 1024, 0, stream>>>(pads, rowstart, N_NODES);
    alloc_b<<<(N_NODES + 3) / 4, 256, 0, stream>>>(rowstart, pd, seg, csr_col, N_NODES);

    // CSR scatter || h0f -> dinv-pre-scaled bf16 h0b
    scatter_scale<<<HBLK + G_SCALE, 256, 0, stream>>>(row, col, cnt, rowstart, rank,
                                                      csr_col, h0f, dinv, h0b);

    int sgrid = 2 * ((N_NODES + 3) / 4); // plane = bid&1, 4 nodes/block
    // out1b = dinv*(h0 + w0 * spmm(h0)), h0 reconstructed from h0b
    spmm_kernel<<<sgrid, 256, 0, stream>>>(h0b, seg, csr_col, dinv, sq, h0b,
                                           wts, 0, nullptr, nullptr, out1b, N_NODES);
    // t2b = dinv*spmm(out1)
    spmm_kernel<<<sgrid, 256, 0, stream>>>(out1b, seg, csr_col, dinv, sq, nullptr,
                                           wts, 0, t2b, nullptr, nullptr, N_NODES);
    // out = out1 + w1 * spmm(t2), out1 reconstructed from out1b  (fp32 final)
    spmm_kernel<<<sgrid, 256, 0, stream>>>(t2b, seg, csr_col, dinv, sq, out1b,
                                           wts, 1, nullptr, out, nullptr, N_NODES);
}

// Round 10
// 179.313 us; speedup vs baseline: 1.4243x; 1.0780x over previous
//
#include <hip/hip_runtime.h>

#define N_NODES 10000
#define E_EDGES 640000
#define IN_CH   512
#define OUT_CH  256
#define HALF_CH 128
#define CSR_CAP (E_EDGES + 16 * N_NODES + 128)  // pad-16 capacity + prefetch slack (u16 entries)
#define G_GEMM_X 157                            // ceil(10000/64)
#define G_GEMM  (G_GEMM_X * 2)                  // x2 planes
#define HBLK    125                             // histogram/scatter chunks
#define EPB     5120                            // edges per chunk: 125*5120 = 640000
#define G_CONVX 2500                            // x-convert blocks (2048 f32 each)
#define G_CONVW 64                              // w-convert blocks
#define G_AB    40                              // alloc_b blocks (256 rows each)

typedef short bf16x8 __attribute__((ext_vector_type(8)));
typedef float f32x4  __attribute__((ext_vector_type(4)));

__device__ __forceinline__ unsigned short f2b(float f) {
    unsigned int u = __float_as_uint(f);
    return (unsigned short)((u + 0x7FFFu + ((u >> 16) & 1u)) >> 16);
}
__device__ __forceinline__ float lo16(unsigned int u) { return __uint_as_float(u << 16); }
__device__ __forceinline__ float hi16(unsigned int u) { return __uint_as_float(u & 0xFFFF0000u); }
__device__ __forceinline__ float b2f(unsigned short u) { return __uint_as_float(((unsigned int)u) << 16); }

// ---------------- conv (x,w -> bf16, hoisted) || LDS-hist rank (R9-verified) ------------
__global__ __launch_bounds__(256) void conv_hist(const float* __restrict__ x,
                                                 const float* __restrict__ w,
                                                 unsigned short* __restrict__ xb,
                                                 unsigned short* __restrict__ wb,
                                                 const int* __restrict__ row,
                                                 int* __restrict__ cnt,          // [HBLK][N]
                                                 unsigned short* __restrict__ rank) {
    int bid = blockIdx.x;
    int tid = threadIdx.x;
    if (bid < HBLK) {
        // ---- hist path ----
        __shared__ int hist[N_NODES];
        for (int i = tid; i < N_NODES; i += 256) hist[i] = 0;
        __syncthreads();
        int ebase = bid * EPB;
        for (int i = tid; i < EPB; i += 256) {
            int r = row[ebase + i];
            rank[ebase + i] = (unsigned short)atomicAdd(&hist[r], 1);
        }
        __syncthreads();
        int* cb = cnt + (size_t)bid * N_NODES;
        for (int i = tid; i < N_NODES; i += 256) cb[i] = hist[i];
        return;
    }
    // ---- convert path: 8 f32 -> 8 bf16 per thread ----
    int u = bid - HBLK;
    const float* src;
    unsigned short* dst;
    size_t base;
    if (u < G_CONVX) { src = x;  dst = xb; base = (size_t)u * 2048 + tid * 8; }
    else             { src = w;  dst = wb; base = (size_t)(u - G_CONVX) * 2048 + tid * 8; }
    float4 a = *(const float4*)(src + base);
    float4 b = *(const float4*)(src + base + 4);
    ushort4 lo, hi;
    lo.x = f2b(a.x); lo.y = f2b(a.y); lo.z = f2b(a.z); lo.w = f2b(a.w);
    hi.x = f2b(b.x); hi.y = f2b(b.y); hi.z = f2b(b.z); hi.w = f2b(b.w);
    *(ushort4*)(dst + base) = lo;
    *(ushort4*)(dst + base + 4) = hi;
}

// ---------------- alloc_a2: THREAD-per-row, coalesced [HBLK][N] walk --------------------
// Consecutive threads read consecutive addresses (was: 64 lanes x 40KB stride = 160MB of
// line traffic; now 10MB). 8-deep load unroll keeps 8 independent loads in flight.
// Writes local exclusive per-block base in place; degree = final running sum.
__global__ __launch_bounds__(256) void alloc_a2(int* __restrict__ cnt,   // [HBLK][N]
                                                int2* __restrict__ pd,
                                                float* __restrict__ dinv, float* __restrict__ sq,
                                                int* __restrict__ pads, int n) {
    int r = blockIdx.x * 256 + threadIdx.x;
    if (r >= n) return;
    int run = 0;
    int b0 = 0;
    for (; b0 + 8 <= HBLK; b0 += 8) {
        int c[8];
        #pragma unroll
        for (int j = 0; j < 8; j++) c[j] = cnt[(size_t)(b0 + j) * N_NODES + r];
        #pragma unroll
        for (int j = 0; j < 8; j++) {
            cnt[(size_t)(b0 + j) * N_NODES + r] = run;
            run += c[j];
        }
    }
    for (; b0 < HBLK; b0++) {
        int c = cnt[(size_t)b0 * N_NODES + r];
        cnt[(size_t)b0 * N_NODES + r] = run;
        run += c;
    }
    int d = run;
    int pad = (d + 15) & ~15;
    dinv[r] = (d > 0) ? rsqrtf((float)d) : 0.0f;
    sq[r]   = (d > 0) ? sqrtf((float)d) : 0.0f;
    pd[r] = make_int2(d, pad);
    pads[r] = pad;
}

// ---------------- scan_pads: single-block exclusive scan of 10000 pads ----------------
__global__ __launch_bounds__(1024) void scan_pads(const int* __restrict__ pads,
                                                  int* __restrict__ rowstart, int n) {
    __shared__ int ls[1024];
    int t = threadIdx.x;
    int base = t * 10;                  // 1000 threads x 10 elements covers 10000
    int loc[10];
    int sum = 0;
    if (base < n) {
        #pragma unroll
        for (int i = 0; i < 10; i++) { loc[i] = pads[base + i]; sum += loc[i]; }
    }
    ls[t] = sum;
    __syncthreads();
    for (int off = 1; off < 1024; off <<= 1) {
        int v = (t >= off) ? ls[t - off] : 0;
        __syncthreads();
        ls[t] += v;
        __syncthreads();
    }
    if (base < n) {
        int run = ls[t] - sum;          // exclusive block prefix
        #pragma unroll
        for (int i = 0; i < 10; i++) { rowstart[base + i] = run; run += loc[i]; }
    }
}

// ---------------- D4: GEMM (writes pre-scaled bf16 h0b directly) || scatter || alloc_b --
// dinv ready (alloc_a2 ran) -> h0f f32 round-trip + scale pass deleted. Scatter and
// alloc_b (seg + sentinels) overlap with GEMM compute in the same dispatch.
__global__ __launch_bounds__(256) void gemm_scatter_ab(const unsigned short* __restrict__ xb,
                                                       const unsigned short* __restrict__ wb,
                                                       const float* __restrict__ bias,
                                                       const float* __restrict__ dinv,
                                                       unsigned short* __restrict__ h0b,
                                                       const int* __restrict__ row,
                                                       const int* __restrict__ col,
                                                       const int* __restrict__ base, // [HBLK][N]
                                                       const int* __restrict__ rowstart,
                                                       const unsigned short* __restrict__ rank,
                                                       unsigned short* __restrict__ csr_col,
                                                       const int2* __restrict__ pd,
                                                       int2* __restrict__ seg) {
    __shared__ __align__(16) char smem[40960];   // union: gemm 27.6KB tiles | scatter 40KB
    int bid = blockIdx.x;
    int tid = threadIdx.x;
    if (bid >= G_GEMM + HBLK) {
        // ---- alloc_b path: seg + pad sentinels, thread-per-row ----
        int r = (bid - G_GEMM - HBLK) * 256 + tid;
        if (r >= N_NODES) return;
        int s = rowstart[r];
        int2 pd_ = pd[r];
        seg[r] = make_int2(s, s + pd_.y);
        for (int j = pd_.x; j < pd_.y; j++) csr_col[s + j] = (unsigned short)N_NODES;
        return;
    }
    if (bid >= G_GEMM) {
        // ---- scatter path: stage absolutized base row into 40KB LDS, then scatter ----
        int sb = bid - G_GEMM;
        int* bs = (int*)smem;
        const int4* cb4 = (const int4*)(base + (size_t)sb * N_NODES);
        const int4* rs4 = (const int4*)rowstart;
        for (int i = tid; i < N_NODES / 4; i += 256) {   // 2500 int4, coalesced
            int4 c = cb4[i];
            int4 r = rs4[i];
            int4 o;
            o.x = c.x + r.x; o.y = c.y + r.y; o.z = c.z + r.z; o.w = c.w + r.w;
            ((int4*)bs)[i] = o;
        }
        __syncthreads();
        int ebase = sb * EPB;
        for (int i = tid; i < EPB; i += 256) {
            int e = ebase + i;
            int p = bs[row[e]] + (int)rank[e];
            csr_col[p] = (unsigned short)col[e];
        }
        return;
    }
    // ---- gemm path: copy-only staging, epilogue writes f2b(acc*dinv) bf16 ----
    typedef unsigned short us72[72];
    us72* As = (us72*)smem;                     // [64][72]
    us72* Bs = (us72*)(smem + 64 * 72 * 2);     // [128][72]
    int bx = bid % G_GEMM_X;
    int plane = bid / G_GEMM_X;
    int wave = tid >> 6, lane = tid & 63, quad = lane >> 4, l16 = lane & 15;
    int row0 = bx * 64;
    int n0 = plane * 128;
    unsigned short* h0b_p = h0b + (size_t)plane * (N_NODES + 1) * HALF_CH;

    int ar = tid >> 2;
    int aseg = (tid & 3) * 16;
    int br = tid >> 1;
    int bseg = (tid & 1) * 32;

    f32x4 acc[8] = {};
    for (int k0 = 0; k0 < IN_CH; k0 += 64) {
        {
            int gr = row0 + ar;
            if (gr < N_NODES) {
                const uint4* src = (const uint4*)(xb + (size_t)gr * IN_CH + k0 + aseg);
                *(uint4*)&As[ar][aseg]     = src[0];
                *(uint4*)&As[ar][aseg + 8] = src[1];
            } else {
                uint4 z = {0, 0, 0, 0};
                *(uint4*)&As[ar][aseg]     = z;
                *(uint4*)&As[ar][aseg + 8] = z;
            }
        }
        {
            const uint4* src = (const uint4*)(wb + (size_t)(n0 + br) * IN_CH + k0 + bseg);
            *(uint4*)&Bs[br][bseg]      = src[0];
            *(uint4*)&Bs[br][bseg + 8]  = src[1];
            *(uint4*)&Bs[br][bseg + 16] = src[2];
            *(uint4*)&Bs[br][bseg + 24] = src[3];
        }
        __syncthreads();
        #pragma unroll
        for (int kk = 0; kk < 2; kk++) {
            bf16x8 a = *(const bf16x8*)&As[wave * 16 + l16][kk * 32 + quad * 8];
            #pragma unroll
            for (int t = 0; t < 8; t++) {
                bf16x8 b = *(const bf16x8*)&Bs[t * 16 + l16][kk * 32 + quad * 8];
                acc[t] = __builtin_amdgcn_mfma_f32_16x16x32_bf16(a, b, acc[t], 0, 0, 0);
            }
        }
        __syncthreads();
    }
    #pragma unroll
    for (int t = 0; t < 8; t++) {
        int lcol = t * 16 + l16;
        float bv = bias[n0 + lcol];
        #pragma unroll
        for (int r = 0; r < 4; r++) {
            int grow = row0 + wave * 16 + quad * 4 + r;
            if (grow < N_NODES) {
                float v = acc[t][r] + bv;
                h0b_p[(size_t)grow * HALF_CH + lcol] = f2b(v * dinv[grow]);
            }
        }
    }
    // zero the pad row (sentinel gather target) — one block per plane
    if (bx == 0 && tid < 64)
        ((unsigned int*)(h0b_p + (size_t)N_NODES * HALF_CH))[tid] = 0u;
}

// ---------------- SpMM: XCD-plane-partitioned, double-buffered gathers (csr u16) --------
// (R9-verified, unchanged)
__global__ __launch_bounds__(256) void spmm_kernel(const unsigned short* __restrict__ hb,
                                                   const int2* __restrict__ seg,
                                                   const unsigned short* __restrict__ csr_col,
                                                   const float* __restrict__ dinv,
                                                   const float* __restrict__ sq,
                                                   const unsigned short* __restrict__ prev_b,
                                                   const float* __restrict__ wts, int widx,
                                                   unsigned short* __restrict__ yb_out,
                                                   float* __restrict__ axpy_out,
                                                   unsigned short* __restrict__ axpyb_out,
                                                   int n) {
    int plane = blockIdx.x & 1;
    int node = (blockIdx.x >> 1) * 4 + (threadIdx.x >> 6);
    int lane = threadIdx.x & 63;
    if (node >= n) return;
    int sub = lane >> 4, l16 = lane & 15;
    size_t pstride = (size_t)(n + 1) * HALF_CH;
    const unsigned short* hp = hb + (size_t)plane * pstride;

    int2 se = seg[node];
    int s = se.x, e = se.y;
    float acc[8] = {0.f, 0.f, 0.f, 0.f, 0.f, 0.f, 0.f, 0.f};
    if (s < e) {
        int cA0 = csr_col[s + 0  + sub];
        int cA1 = csr_col[s + 4  + sub];
        int cA2 = csr_col[s + 8  + sub];
        int cA3 = csr_col[s + 12 + sub];
        uint4 vA0 = *(const uint4*)(hp + (size_t)cA0 * HALF_CH + l16 * 8);
        uint4 vA1 = *(const uint4*)(hp + (size_t)cA1 * HALF_CH + l16 * 8);
        uint4 vA2 = *(const uint4*)(hp + (size_t)cA2 * HALF_CH + l16 * 8);
        uint4 vA3 = *(const uint4*)(hp + (size_t)cA3 * HALF_CH + l16 * 8);
        int cB0 = csr_col[s + 16 + sub];   // slack-safe beyond e (never dereferenced then)
        int cB1 = csr_col[s + 20 + sub];
        int cB2 = csr_col[s + 24 + sub];
        int cB3 = csr_col[s + 28 + sub];
        int p = s;
        while (p + 16 < e) {
            uint4 vB0 = *(const uint4*)(hp + (size_t)cB0 * HALF_CH + l16 * 8);
            uint4 vB1 = *(const uint4*)(hp + (size_t)cB1 * HALF_CH + l16 * 8);
            uint4 vB2 = *(const uint4*)(hp + (size_t)cB2 * HALF_CH + l16 * 8);
            uint4 vB3 = *(const uint4*)(hp + (size_t)cB3 * HALF_CH + l16 * 8);
            int pn = p + 32;
            int cC0 = csr_col[pn + 0  + sub];   // prefetch 2 groups ahead (slack-safe)
            int cC1 = csr_col[pn + 4  + sub];
            int cC2 = csr_col[pn + 8  + sub];
            int cC3 = csr_col[pn + 12 + sub];
            acc[0] += lo16(vA0.x) + lo16(vA1.x) + lo16(vA2.x) + lo16(vA3.x);
            acc[1] += hi16(vA0.x) + hi16(vA1.x) + hi16(vA2.x) + hi16(vA3.x);
            acc[2] += lo16(vA0.y) + lo16(vA1.y) + lo16(vA2.y) + lo16(vA3.y);
            acc[3] += hi16(vA0.y) + hi16(vA1.y) + hi16(vA2.y) + hi16(vA3.y);
            acc[4] += lo16(vA0.z) + lo16(vA1.z) + lo16(vA2.z) + lo16(vA3.z);
            acc[5] += hi16(vA0.z) + hi16(vA1.z) + hi16(vA2.z) + hi16(vA3.z);
            acc[6] += lo16(vA0.w) + lo16(vA1.w) + lo16(vA2.w) + lo16(vA3.w);
            acc[7] += hi16(vA0.w) + hi16(vA1.w) + hi16(vA2.w) + hi16(vA3.w);
            vA0 = vB0; vA1 = vB1; vA2 = vB2; vA3 = vB3;
            cB0 = cC0; cB1 = cC1; cB2 = cC2; cB3 = cC3;
            p += 16;
        }
        acc[0] += lo16(vA0.x) + lo16(vA1.x) + lo16(vA2.x) + lo16(vA3.x);
        acc[1] += hi16(vA0.x) + hi16(vA1.x) + hi16(vA2.x) + hi16(vA3.x);
        acc[2] += lo16(vA0.y) + lo16(vA1.y) + lo16(vA2.y) + lo16(vA3.y);
        acc[3] += hi16(vA0.y) + hi16(vA1.y) + hi16(vA2.y) + hi16(vA3.y);
        acc[4] += lo16(vA0.z) + lo16(vA1.z) + lo16(vA2.z) + lo16(vA3.z);
        acc[5] += hi16(vA0.z) + hi16(vA1.z) + hi16(vA2.z) + hi16(vA3.z);
        acc[6] += lo16(vA0.w) + lo16(vA1.w) + lo16(vA2.w) + lo16(vA3.w);
        acc[7] += hi16(vA0.w) + hi16(vA1.w) + hi16(vA2.w) + hi16(vA3.w);
    }
    #pragma unroll
    for (int k = 0; k < 8; k++) {
        acc[k] += __shfl_xor(acc[k], 16, 64);
        acc[k] += __shfl_xor(acc[k], 32, 64);
    }
    if (sub != 0) return;

    float di = dinv[node];
    float y[8];
    #pragma unroll
    for (int k = 0; k < 8; k++) y[k] = di * acc[k];

    size_t pbase = (size_t)plane * pstride + (size_t)node * HALF_CH + l16 * 8;
    size_t padrow = (size_t)plane * pstride + (size_t)n * HALF_CH + l16 * 8;
    if (yb_out) {
        ushort4 o0, o1;
        o0.x = f2b(di * y[0]); o0.y = f2b(di * y[1]); o0.z = f2b(di * y[2]); o0.w = f2b(di * y[3]);
        o1.x = f2b(di * y[4]); o1.y = f2b(di * y[5]); o1.z = f2b(di * y[6]); o1.w = f2b(di * y[7]);
        *(ushort4*)(yb_out + pbase) = o0;
        *(ushort4*)(yb_out + pbase + 4) = o1;
        if (node == 0) {
            ushort4 z = {0, 0, 0, 0};
            *(ushort4*)(yb_out + padrow) = z;
            *(ushort4*)(yb_out + padrow + 4) = z;
        }
    }
    if (prev_b) {
        float wk = wts[widx];
        float sqn = sq[node];
        ushort4 p0 = *(const ushort4*)(prev_b + pbase);
        ushort4 p1 = *(const ushort4*)(prev_b + pbase + 4);
        float o[8];
        o[0] = b2f(p0.x) * sqn + wk * y[0];
        o[1] = b2f(p0.y) * sqn + wk * y[1];
        o[2] = b2f(p0.z) * sqn + wk * y[2];
        o[3] = b2f(p0.w) * sqn + wk * y[3];
        o[4] = b2f(p1.x) * sqn + wk * y[4];
        o[5] = b2f(p1.y) * sqn + wk * y[5];
        o[6] = b2f(p1.z) * sqn + wk * y[6];
        o[7] = b2f(p1.w) * sqn + wk * y[7];
        if (axpy_out) {
            size_t fbase = (size_t)node * OUT_CH + plane * HALF_CH + l16 * 8;
            float4 f0 = {o[0], o[1], o[2], o[3]};
            float4 f1 = {o[4], o[5], o[6], o[7]};
            *(float4*)(axpy_out + fbase) = f0;
            *(float4*)(axpy_out + fbase + 4) = f1;
        }
        if (axpyb_out) {
            ushort4 b0, b1;
            b0.x = f2b(di * o[0]); b0.y = f2b(di * o[1]); b0.z = f2b(di * o[2]); b0.w = f2b(di * o[3]);
            b1.x = f2b(di * o[4]); b1.y = f2b(di * o[5]); b1.z = f2b(di * o[6]); b1.w = f2b(di * o[7]);
            *(ushort4*)(axpyb_out + pbase) = b0;
            *(ushort4*)(axpyb_out + pbase + 4) = b1;
            if (node == 0) {
                ushort4 z = {0, 0, 0, 0};
                *(ushort4*)(axpyb_out + padrow) = z;
                *(ushort4*)(axpyb_out + padrow + 4) = z;
            }
        }
    }
}

extern "C" void kernel_launch(void* const* d_in, const int* in_sizes, int n_in,
                              void* d_out, int out_size, void* d_ws, size_t ws_size,
                              hipStream_t stream) {
    const float* x     = (const float*)d_in[0];
    const int*   ei    = (const int*)d_in[1];   // [2, E]
    const float* lin_w = (const float*)d_in[2]; // [OUT_CH, IN_CH]
    const float* lin_b = (const float*)d_in[3]; // [OUT_CH]
    const float* wts   = (const float*)d_in[4]; // [K]
    float* out = (float*)d_out;

    char* ws = (char*)d_ws;
    size_t off = 0;
    auto alloc = [&](size_t bytes) -> void* {
        void* p = ws + off;
        off += (bytes + 255) & ~(size_t)255;
        return p;
    };
    int*   cnt      = (int*)  alloc((size_t)HBLK * N_NODES * 4);  // [HBLK][N] counts->bases
    unsigned short* rank = (unsigned short*)alloc((size_t)E_EDGES * 2);
    int2*  pd       = (int2*) alloc((size_t)N_NODES * 8);
    int*   pads     = (int*)  alloc((size_t)N_NODES * 4);
    int*   rowstart = (int*)  alloc((size_t)N_NODES * 4);
    int2*  seg      = (int2*) alloc((size_t)N_NODES * 8);
    float* dinv     = (float*)alloc(N_NODES * 4);
    float* sq       = (float*)alloc(N_NODES * 4);
    unsigned short* csr_col = (unsigned short*)alloc((size_t)CSR_CAP * 2);  // u16 cols
    unsigned short* xb = (unsigned short*)alloc((size_t)N_NODES * IN_CH * 2);  // bf16 x
    unsigned short* wb = (unsigned short*)alloc((size_t)OUT_CH * IN_CH * 2);   // bf16 w
    unsigned short* h0b   = (unsigned short*)alloc((size_t)2 * (N_NODES + 1) * HALF_CH * 2);
    unsigned short* out1b = (unsigned short*)alloc((size_t)2 * (N_NODES + 1) * HALF_CH * 2);
    unsigned short* t2b   = (unsigned short*)alloc((size_t)2 * (N_NODES + 1) * HALF_CH * 2);

    const int* row = ei;
    const int* col = ei + E_EDGES;

    // D1: hist || x/w bf16 conversion (all independent)
    conv_hist<<<HBLK + G_CONVX + G_CONVW, 256, 0, stream>>>(x, lin_w, xb, wb,
                                                            row, cnt, rank);
    // D2: coalesced degree/prefix pass (thread-per-row over [HBLK][N])
    alloc_a2<<<(N_NODES + 255) / 256, 256, 0, stream>>>(cnt, pd, dinv, sq, pads, N_NODES);
    // D3: exclusive scan of padded degrees
    scan_pads<<<1, 1024, 0, stream>>>(pads, rowstart, N_NODES);
    // D4: GEMM (direct pre-scaled bf16 h0b) || CSR scatter || alloc_b
    gemm_scatter_ab<<<G_GEMM + HBLK + G_AB, 256, 0, stream>>>(xb, wb, lin_b, dinv, h0b,
                                                              row, col, cnt, rowstart,
                                                              rank, csr_col, pd, seg);

    int sgrid = 2 * ((N_NODES + 3) / 4); // plane = bid&1, 4 nodes/block
    // out1b = dinv*(h0 + w0 * spmm(h0)), h0 reconstructed from h0b
    spmm_kernel<<<sgrid, 256, 0, stream>>>(h0b, seg, csr_col, dinv, sq, h0b,
                                           wts, 0, nullptr, nullptr, out1b, N_NODES);
    // t2b = dinv*spmm(out1)
    spmm_kernel<<<sgrid, 256, 0, stream>>>(out1b, seg, csr_col, dinv, sq, nullptr,
                                           wts, 0, t2b, nullptr, nullptr, N_NODES);
    // out = out1 + w1 * spmm(t2), out1 reconstructed from out1b  (fp32 final)
    spmm_kernel<<<sgrid, 256, 0, stream>>>(t2b, seg, csr_col, dinv, sq, out1b,
                                           wts, 1, nullptr, out, nullptr, N_NODES);
}